// Round 11
// baseline (62.418 us; speedup 1.0000x reference)
//
#include <hip/hip_runtime.h>
#include <cfloat>

#define HD 1024
#define LS 2048
#define NB 16
#define NCH 128              // chunks per batch
#define LPER (LS / NCH)      // 16 rows per chunk

struct f4 { float x, y, z, w; };

__device__ inline f4 ld4(const float* p) { return *reinterpret_cast<const f4*>(p); }

// direct global->LDS stage: 64 lanes x 16B = 1KB per call; dest = uniform base + lane*16
__device__ inline void stage16(const float* g, float* l) {
    __builtin_amdgcn_global_load_lds(
        (const __attribute__((address_space(1))) void*)g,
        (__attribute__((address_space(3))) void*)(void*)l,
        16, 0, 0);
}

__device__ inline float ftanh(float x) {
    x = fminf(10.f, fmaxf(-10.f, x));
    float t = __expf(2.f * x);
    return 1.f - 2.f * __builtin_amdgcn_rcpf(t + 1.f);
}

__device__ inline float dotTanh(const f4& s, const f4& q, const f4& wc, const f4& v, float covs) {
    return ftanh(s.x + q.x + covs * wc.x) * v.x
         + ftanh(s.y + q.y + covs * wc.y) * v.y
         + ftanh(s.z + q.z + covs * wc.z) * v.z
         + ftanh(s.w + q.w + covs * wc.w) * v.w;
}

__device__ inline float waveReduce(float v) {
    #pragma unroll
    for (int off = 32; off; off >>= 1) v += __shfl_xor(v, off, 64);
    return v;
}

// ---- 1: qf[b][h] = bq[h] + query[b,:] . Wq[h,:]  (block per h) ----
__global__ void qf_kernel(const float* __restrict__ query, const float* __restrict__ Wq,
                          const float* __restrict__ bq, float* __restrict__ qf) {
    int h = blockIdx.x;
    int tid = threadIdx.x;            // 256
    int wv = tid >> 6, lane = tid & 63;
    int k0 = tid * 4;
    f4 w = ld4(Wq + (size_t)h * HD + k0);
    __shared__ float red[4][NB];
    float acc[NB];
    #pragma unroll
    for (int b = 0; b < NB; ++b) {
        f4 q = ld4(query + b * HD + k0);
        acc[b] = w.x * q.x + w.y * q.y + w.z * q.z + w.w * q.w;
    }
    #pragma unroll
    for (int b = 0; b < NB; ++b) {
        float r = waveReduce(acc[b]);
        if (lane == 0) red[wv][b] = r;
    }
    __syncthreads();
    if (tid < NB) {
        float s = red[0][tid] + red[1][tid] + red[2][tid] + red[3][tid];
        qf[tid * HD + h] = s + bq[h];
    }
}

// ---- 2 (fused, overlapped streams): per block = 16 rows of one batch.
//      Compact rows from mask; IMMEDIATELY stage states rows -> LDS (async,
//      address needs only mask); phase A computes energies from reg-staged sf
//      concurrently; one barrier drains staging; phase B = LDS FMA sum. ----
__global__ __launch_bounds__(256) void fusedEC_kernel(
    const float* __restrict__ sf, const float* __restrict__ qf,
    const float* __restrict__ Wc, const float* __restrict__ vv,
    const float* __restrict__ coverage, const int* __restrict__ mask,
    const int* __restrict__ is_cov_p, const float* __restrict__ states,
    float* __restrict__ e_out, float* __restrict__ cpart)
{
    __shared__ float buf[LPER * HD];   // 64 KB states staging
    __shared__ float e_loc[LPER];      // full energies (-1e30 for masked)
    __shared__ float ec[LPER];         // compacted energies
    __shared__ int   ridx[LPER];       // compacted row indices
    __shared__ int   snnz;

    int chunk = blockIdx.x;            // 0..127
    int b = blockIdx.y;                // 0..15
    int tid = threadIdx.x;             // 256
    int wv = tid >> 6, lane = tid & 63;
    int l4 = lane * 4;
    int base_row = b * LS + chunk * LPER;

    // --- compaction (wave 0) ---
    if (tid < 64) {
        int mk = (tid < LPER) ? mask[base_row + tid] : 0;
        unsigned long long bm = __ballot(mk != 0);
        if (tid < LPER) e_loc[tid] = -1e30f;
        if (mk != 0) {
            int pos = __popcll(bm & ((1ull << tid) - 1));
            ridx[pos] = tid;
        }
        if (tid == 0) snnz = __popcll(bm);
    }
    __syncthreads();
    int nnz = snnz;

    // --- issue states staging NOW (depends only on compaction, not energies) ---
    for (int i = wv; i < nnz; i += 4) {
        const float* src = states + (size_t)(base_row + ridx[i]) * HD + l4;
        float* dst = &buf[i * HD];
        stage16(src,       dst);
        stage16(src + 256, dst + 256);
        stage16(src + 512, dst + 512);
        stage16(src + 768, dst + 768);
    }

    // --- phase A (concurrent with staging): energies, 4 compacted rows/wave ---
    int covflag = *is_cov_p;
    int c0 = wv, c1 = wv + 4, c2 = wv + 8, c3 = wv + 12;
    bool p0 = c0 < nnz, p1 = c1 < nnz, p2 = c2 < nnz, p3 = c3 < nnz;
    int r0 = p0 ? ridx[c0] : 0;
    int r1 = p1 ? ridx[c1] : 0;
    int r2 = p2 ? ridx[c2] : 0;
    int r3 = p3 ? ridx[c3] : 0;
    float cov0 = (covflag && p0) ? coverage[base_row + r0] : 0.f;
    float cov1 = (covflag && p1) ? coverage[base_row + r1] : 0.f;
    float cov2 = (covflag && p2) ? coverage[base_row + r2] : 0.f;
    float cov3 = (covflag && p3) ? coverage[base_row + r3] : 0.f;

    const float* qfr = qf + b * HD + l4;
    const float* s0p = sf + (size_t)(base_row + r0) * HD + l4;
    const float* s1p = sf + (size_t)(base_row + r1) * HD + l4;
    const float* s2p = sf + (size_t)(base_row + r2) * HD + l4;
    const float* s3p = sf + (size_t)(base_row + r3) * HD + l4;
    float a0 = 0.f, a1 = 0.f, a2 = 0.f, a3 = 0.f;

    #pragma unroll
    for (int it = 0; it < 4; ++it) {
        int o = it * 256;
        f4 q  = ld4(qfr + o);
        f4 wc = ld4(Wc + o + l4);
        f4 vf = ld4(vv + o + l4);
        f4 s0, s1, s2, s3;
        if (p0) s0 = ld4(s0p + o);
        if (p1) s1 = ld4(s1p + o);
        if (p2) s2 = ld4(s2p + o);
        if (p3) s3 = ld4(s3p + o);
        if (p0) a0 += dotTanh(s0, q, wc, vf, cov0);
        if (p1) a1 += dotTanh(s1, q, wc, vf, cov1);
        if (p2) a2 += dotTanh(s2, q, wc, vf, cov2);
        if (p3) a3 += dotTanh(s3, q, wc, vf, cov3);
    }

    // interleaved cross-lane reductions (4 independent chains pipeline)
    #pragma unroll
    for (int off = 32; off; off >>= 1) {
        a0 += __shfl_xor(a0, off, 64);
        a1 += __shfl_xor(a1, off, 64);
        a2 += __shfl_xor(a2, off, 64);
        a3 += __shfl_xor(a3, off, 64);
    }
    if (lane == 0) {
        if (p0) { ec[c0] = a0; e_loc[r0] = a0; }
        if (p1) { ec[c1] = a1; e_loc[r1] = a1; }
        if (p2) { ec[c2] = a2; e_loc[r2] = a2; }
        if (p3) { ec[c3] = a3; e_loc[r3] = a3; }
    }
    __syncthreads();   // drains staging vmcnt; ec/e_loc visible

    // e_out writeback (independent of phase B)
    if (tid < LPER) e_out[base_row + tid] = e_loc[tid];

    // --- phase B: weighted sum from LDS; weights = exp(ec[i]) computed inline ---
    int h0 = tid * 4;
    const float* bp = &buf[h0];
    float ax = 0.f, ay = 0.f, az = 0.f, aw = 0.f;
    for (int i = 0; i < nnz; i += 4) {
        int j1 = i + 1, j2 = i + 2, j3 = i + 3;
        float w0 = __expf(ec[i]);                         // |e| <= ~26, no overflow
        float w1 = (j1 < nnz) ? __expf(ec[j1]) : 0.f;
        float w2 = (j2 < nnz) ? __expf(ec[j2]) : 0.f;
        float w3 = (j3 < nnz) ? __expf(ec[j3]) : 0.f;
        int k1 = (j1 < nnz) ? j1 : 0;
        int k2 = (j2 < nnz) ? j2 : 0;
        int k3 = (j3 < nnz) ? j3 : 0;
        f4 s0 = ld4(bp + ((size_t)i  << 10));
        f4 s1 = ld4(bp + ((size_t)k1 << 10));
        f4 s2 = ld4(bp + ((size_t)k2 << 10));
        f4 s3 = ld4(bp + ((size_t)k3 << 10));
        ax = fmaf(w0, s0.x, ax); ay = fmaf(w0, s0.y, ay); az = fmaf(w0, s0.z, az); aw = fmaf(w0, s0.w, aw);
        ax = fmaf(w1, s1.x, ax); ay = fmaf(w1, s1.y, ay); az = fmaf(w1, s1.z, az); aw = fmaf(w1, s1.w, aw);
        ax = fmaf(w2, s2.x, ax); ay = fmaf(w2, s2.y, ay); az = fmaf(w2, s2.z, az); aw = fmaf(w2, s2.w, aw);
        ax = fmaf(w3, s3.x, ax); ay = fmaf(w3, s3.y, ay); az = fmaf(w3, s3.z, az); aw = fmaf(w3, s3.w, aw);
    }
    f4 o; o.x = ax; o.y = ay; o.z = az; o.w = aw;
    *reinterpret_cast<f4*>(cpart + ((size_t)(b * NCH + chunk)) * HD + h0) = o;  // unnormalized
}

// ---- 3 (merged): blocks 0..15 = per-batch softmax finalize; blocks 16..79 = cpart reduce ----
__global__ __launch_bounds__(1024) void mid_kernel(
    const float* __restrict__ e, const float* __restrict__ coverage,
    const float* __restrict__ cpart, float* __restrict__ scale,
    float* __restrict__ csum, float* __restrict__ out_align, float* __restrict__ out_newcov)
{
    __shared__ float redm[16], reds[16];
    __shared__ float red4[4][256];
    if (blockIdx.x < 16) {
        int b = blockIdx.x;
        int t = threadIdx.x;              // 1024
        int wv = t >> 6, lane = t & 63;
        float v0 = e[b * LS + t];
        float v1 = e[b * LS + t + 1024];
        float mx = fmaxf(v0, v1);
        #pragma unroll
        for (int off = 32; off; off >>= 1) mx = fmaxf(mx, __shfl_xor(mx, off, 64));
        if (lane == 0) redm[wv] = mx;
        __syncthreads();
        mx = redm[0];
        #pragma unroll
        for (int i = 1; i < 16; ++i) mx = fmaxf(mx, redm[i]);
        float e0 = __expf(v0 - mx), e1 = __expf(v1 - mx);
        float s = e0 + e1;
        #pragma unroll
        for (int off = 32; off; off >>= 1) s += __shfl_xor(s, off, 64);
        if (lane == 0) reds[wv] = s;
        __syncthreads();
        s = 0.f;
        #pragma unroll
        for (int i = 0; i < 16; ++i) s += reds[i];
        float invZ = 1.f / s;
        if (t == 0) scale[b] = __expf(-mx) * invZ;   // = 1 / sum(exp(e))
        int i0 = b * LS + t, i1 = i0 + 1024;
        float p0 = e0 * invZ, p1 = e1 * invZ;
        out_align[i0] = p0;
        out_align[i1] = p1;
        out_newcov[i0] = coverage[i0] + p0;
        out_newcov[i1] = coverage[i1] + p1;
    } else {
        int blk = blockIdx.x - 16;        // 0..63
        int tt = threadIdx.x & 255;
        int g = threadIdx.x >> 8;         // 0..3: each group sums 32 chunks
        int elem = blk * 256 + tt;        // 0..16383 = (b,h)
        int b = elem >> 10, h = elem & 1023;
        const float* p = cpart + (((size_t)(b * NCH + g * 32)) << 10) + h;
        float s = 0.f;
        #pragma unroll
        for (int ch = 0; ch < 32; ++ch) s += p[(size_t)ch << 10];
        red4[g][tt] = s;
        __syncthreads();
        if (g == 0) csum[elem] = red4[0][tt] + red4[1][tt] + red4[2][tt] + red4[3][tt];
    }
}

// ---- 4: attn_h[b][h] = bout[h] + scale[b]*<Wout_c, csum[b]> + <Wout_q, query[b]> ----
__global__ void out_kernel(const float* __restrict__ csum, const float* __restrict__ query,
                           const float* __restrict__ Wout, const float* __restrict__ bout,
                           const float* __restrict__ scale, float* __restrict__ attn) {
    int h = blockIdx.x;
    int tid = threadIdx.x;            // 256
    int wv = tid >> 6, lane = tid & 63;
    int j0 = tid * 8;
    const float* wr = Wout + (size_t)h * (2 * HD);
    f4 w0 = ld4(wr + j0);
    f4 w1 = ld4(wr + j0 + 4);
    const float* src = (j0 < HD) ? (csum + j0) : (query + j0 - HD);   // waves 0,1: csum; 2,3: query
    __shared__ float red[4][NB];
    float acc[NB];
    #pragma unroll
    for (int b = 0; b < NB; ++b) {
        f4 x0 = ld4(src + b * HD);
        f4 x1 = ld4(src + b * HD + 4);
        acc[b] = w0.x * x0.x + w0.y * x0.y + w0.z * x0.z + w0.w * x0.w
               + w1.x * x1.x + w1.y * x1.y + w1.z * x1.z + w1.w * x1.w;
    }
    #pragma unroll
    for (int b = 0; b < NB; ++b) {
        float r = waveReduce(acc[b]);
        if (lane == 0) red[wv][b] = r;
    }
    __syncthreads();
    if (tid < NB) {
        float cpartial = red[0][tid] + red[1][tid];   // csum part
        float qpartial = red[2][tid] + red[3][tid];   // query part
        attn[tid * HD + h] = cpartial * scale[tid] + qpartial + bout[h];
    }
}

extern "C" void kernel_launch(void* const* d_in, const int* in_sizes, int n_in,
                              void* d_out, int out_size, void* d_ws, size_t ws_size,
                              hipStream_t stream) {
    const float* query    = (const float*)d_in[0];
    const float* states   = (const float*)d_in[1];
    const float* sf       = (const float*)d_in[2];
    const float* coverage = (const float*)d_in[3];
    const int*   mask     = (const int*)d_in[4];
    const int*   is_cov   = (const int*)d_in[5];
    const float* Wq       = (const float*)d_in[6];
    const float* bq       = (const float*)d_in[7];
    const float* Wc       = (const float*)d_in[8];
    const float* v        = (const float*)d_in[9];
    const float* Wout     = (const float*)d_in[10];
    const float* bout     = (const float*)d_in[11];

    float* out      = (float*)d_out;
    float* attn     = out;                 // (16,1,1024)  = 16384
    float* newcov   = out + 16384;         // (16,2048,1)  = 32768
    float* alignout = out + 49152;         // (16,2048,1)  = 32768

    float* w  = (float*)d_ws;
    float* qf      = w;                          // 16*1024     = 16384
    float* e       = w + 16384;                  // 16*2048     = 32768
    float* cpart   = w + 49152;                  // 16*128*1024 = 2097152
    float* scale   = w + 49152 + 2097152;        // 16
    float* csum    = scale + 16;                 // 16*1024

    // 1: query features (reads Wq once, 4 MB)
    qf_kernel<<<dim3(HD), dim3(256), 0, stream>>>(query, Wq, bq, qf);
    // 2: fused energies + raw-exp weighted partial contexts, sf/states streams overlapped
    fusedEC_kernel<<<dim3(NCH, NB), dim3(256), 0, stream>>>(
        sf, qf, Wc, v, coverage, mask, is_cov, states, e, cpart);
    // 3: softmax finalize (align/newcov/scale) + cpart reduce, role-split
    mid_kernel<<<dim3(80), dim3(1024), 0, stream>>>(e, coverage, cpart, scale, csum, alignout, newcov);
    // 4: output projection (reads Wout once, 8 MB)
    out_kernel<<<dim3(HD), dim3(256), 0, stream>>>(csum, query, Wout, bout, scale, attn);
}

// Round 12
// 55.482 us; speedup vs baseline: 1.1250x; 1.1250x over previous
//
#include <hip/hip_runtime.h>
#include <cfloat>

#define HD 1024
#define LS 2048
#define NB 16
#define LCHUNK 64            // chunks per batch (32 rows each)
#define LPER   (LS / LCHUNK) // 32 rows per chunk

struct f4 { float x, y, z, w; };

__device__ inline f4 ld4(const float* p) { return *reinterpret_cast<const f4*>(p); }

__device__ inline float ftanh(float x) {
    x = fminf(10.f, fmaxf(-10.f, x));
    float t = __expf(2.f * x);
    return 1.f - 2.f * __builtin_amdgcn_rcpf(t + 1.f);
}

__device__ inline float dotTanh(const f4& s, const f4& q, const f4& wc, const f4& v, float covs) {
    return ftanh(s.x + q.x + covs * wc.x) * v.x
         + ftanh(s.y + q.y + covs * wc.y) * v.y
         + ftanh(s.z + q.z + covs * wc.z) * v.z
         + ftanh(s.w + q.w + covs * wc.w) * v.w;
}

__device__ inline float waveReduce(float v) {
    #pragma unroll
    for (int off = 32; off; off >>= 1) v += __shfl_xor(v, off, 64);
    return v;
}

// ---- 1: qf[b][h] = bq[h] + query[b,:] . Wq[h,:]  (block per h) ----
__global__ void qf_kernel(const float* __restrict__ query, const float* __restrict__ Wq,
                          const float* __restrict__ bq, float* __restrict__ qf) {
    int h = blockIdx.x;
    int tid = threadIdx.x;            // 256
    int wv = tid >> 6, lane = tid & 63;
    int k0 = tid * 4;
    f4 w = ld4(Wq + (size_t)h * HD + k0);
    __shared__ float red[4][NB];
    float acc[NB];
    #pragma unroll
    for (int b = 0; b < NB; ++b) {
        f4 q = ld4(query + b * HD + k0);
        acc[b] = w.x * q.x + w.y * q.y + w.z * q.z + w.w * q.w;
    }
    #pragma unroll
    for (int b = 0; b < NB; ++b) {
        float r = waveReduce(acc[b]);
        if (lane == 0) red[wv][b] = r;
    }
    __syncthreads();
    if (tid < NB) {
        float s = red[0][tid] + red[1][tid] + red[2][tid] + red[3][tid];
        qf[tid * HD + h] = s + bq[h];
    }
}

// ---- 2 (fused): per block = 32 rows of one batch.
//      Phase A: energies (8 rows/wave, interleaved reductions), mask-skipped.
//      Phase B: raw-exp weighted states partial (compaction + 8-deep pipeline). ----
__global__ __launch_bounds__(256) void fusedEC_kernel(
    const float* __restrict__ sf, const float* __restrict__ qf,
    const float* __restrict__ Wc, const float* __restrict__ vv,
    const float* __restrict__ coverage, const int* __restrict__ mask,
    const int* __restrict__ is_cov_p, const float* __restrict__ states,
    float* __restrict__ e_out, float* __restrict__ cpart)
{
    int chunk = blockIdx.x;                 // 0..63
    int b = blockIdx.y;                     // 0..15
    int tid = threadIdx.x;                  // 256
    int wv = tid >> 6, lane = tid & 63;
    int l4 = lane * 4;
    int base_row = b * LS + chunk * LPER;   // 32 rows
    int row0 = base_row + wv * 8;           // this wave's 8 rows

    __shared__ float e_loc[LPER];

    // --- phase A: energies ---
    int covflag = *is_cov_p;
    int4 mk0 = *reinterpret_cast<const int4*>(mask + row0);
    int4 mk1 = *reinterpret_cast<const int4*>(mask + row0 + 4);
    bool m[8] = { mk0.x != 0, mk0.y != 0, mk0.z != 0, mk0.w != 0,
                  mk1.x != 0, mk1.y != 0, mk1.z != 0, mk1.w != 0 };
    float cov[8];
    #pragma unroll
    for (int r = 0; r < 8; ++r) cov[r] = (covflag && m[r]) ? coverage[row0 + r] : 0.f;

    const float* qfr = qf + b * HD + l4;
    const float* ps = sf + (size_t)row0 * HD + l4;
    float acc[8] = {0.f, 0.f, 0.f, 0.f, 0.f, 0.f, 0.f, 0.f};

    #pragma unroll
    for (int it = 0; it < 4; ++it) {
        int o = it * 256;
        // shared operands: L1-hot reloads, keeps VGPR low
        f4 q  = ld4(qfr + o);
        f4 wc = ld4(Wc + o + l4);
        f4 vf = ld4(vv + o + l4);
        f4 s[8];
        #pragma unroll
        for (int r = 0; r < 8; ++r) if (m[r]) s[r] = ld4(ps + (size_t)r * HD + o);
        #pragma unroll
        for (int r = 0; r < 8; ++r) if (m[r]) acc[r] += dotTanh(s[r], q, wc, vf, cov[r]);
    }

    // interleaved cross-lane reductions (8 independent chains pipeline)
    #pragma unroll
    for (int off = 32; off; off >>= 1) {
        #pragma unroll
        for (int r = 0; r < 8; ++r) acc[r] += __shfl_xor(acc[r], off, 64);
    }
    if (lane == 0) {
        float ev[8];
        #pragma unroll
        for (int r = 0; r < 8; ++r) ev[r] = m[r] ? acc[r] : -1e30f;
        f4 o0, o1;
        o0.x = ev[0]; o0.y = ev[1]; o0.z = ev[2]; o0.w = ev[3];
        o1.x = ev[4]; o1.y = ev[5]; o1.z = ev[6]; o1.w = ev[7];
        *reinterpret_cast<f4*>(e_out + row0) = o0;
        *reinterpret_cast<f4*>(e_out + row0 + 4) = o1;
        #pragma unroll
        for (int r = 0; r < 8; ++r) e_loc[wv * 8 + r] = ev[r];
    }
    __syncthreads();

    // --- phase B: compacted raw-exp weighted states accumulation, 8-deep ---
    __shared__ float wq[LPER];
    __shared__ int ridx[LPER];
    __shared__ int snnz;
    if (tid < 64) {                   // wave 0 compacts nonzero rows
        float ev = (tid < LPER) ? e_loc[tid] : -1e30f;
        float w = __expf(ev);         // masked -> exp(-1e30) = 0
        unsigned long long bm = __ballot(w != 0.f);
        if (w != 0.f) {
            int pos = __popcll(bm & ((1ull << tid) - 1));
            wq[pos] = w;
            ridx[pos] = tid;
        }
        if (tid == 0) snnz = __popcll(bm);
    }
    __syncthreads();
    int nnz = snnz;
    int h0 = tid * 4;
    const float* sbase = states + (size_t)base_row * HD + h0;
    float ax = 0.f, ay = 0.f, az = 0.f, aw = 0.f;
    for (int i = 0; i < nnz; i += 8) {
        float w8[8];
        int   r8[8];
        #pragma unroll
        for (int j = 0; j < 8; ++j) {
            int idx = i + j;
            bool ok = idx < nnz;
            w8[j] = ok ? wq[idx] : 0.f;
            r8[j] = ok ? ridx[idx] : ridx[i];
        }
        f4 s8[8];
        #pragma unroll
        for (int j = 0; j < 8; ++j) s8[j] = ld4(sbase + ((size_t)r8[j] << 10));
        #pragma unroll
        for (int j = 0; j < 8; ++j) {
            ax = fmaf(w8[j], s8[j].x, ax);
            ay = fmaf(w8[j], s8[j].y, ay);
            az = fmaf(w8[j], s8[j].z, az);
            aw = fmaf(w8[j], s8[j].w, aw);
        }
    }
    f4 o; o.x = ax; o.y = ay; o.z = az; o.w = aw;
    *reinterpret_cast<f4*>(cpart + ((size_t)(b * LCHUNK + chunk)) * HD + h0) = o;  // unnormalized
}

// ---- 3 (merged): blocks 0..15 = per-batch softmax finalize; blocks 16..79 = cpart reduce ----
__global__ __launch_bounds__(1024) void mid_kernel(
    const float* __restrict__ e, const float* __restrict__ coverage,
    const float* __restrict__ cpart, float* __restrict__ scale,
    float* __restrict__ csum, float* __restrict__ out_align, float* __restrict__ out_newcov)
{
    __shared__ float redm[16], reds[16];
    __shared__ float red4[4][256];
    if (blockIdx.x < 16) {
        int b = blockIdx.x;
        int t = threadIdx.x;              // 1024
        int wv = t >> 6, lane = t & 63;
        float v0 = e[b * LS + t];
        float v1 = e[b * LS + t + 1024];
        float mx = fmaxf(v0, v1);
        #pragma unroll
        for (int off = 32; off; off >>= 1) mx = fmaxf(mx, __shfl_xor(mx, off, 64));
        if (lane == 0) redm[wv] = mx;
        __syncthreads();
        mx = redm[0];
        #pragma unroll
        for (int i = 1; i < 16; ++i) mx = fmaxf(mx, redm[i]);
        float e0 = __expf(v0 - mx), e1 = __expf(v1 - mx);
        float s = e0 + e1;
        #pragma unroll
        for (int off = 32; off; off >>= 1) s += __shfl_xor(s, off, 64);
        if (lane == 0) reds[wv] = s;
        __syncthreads();
        s = 0.f;
        #pragma unroll
        for (int i = 0; i < 16; ++i) s += reds[i];
        float invZ = 1.f / s;
        if (t == 0) scale[b] = __expf(-mx) * invZ;   // = 1 / sum(exp(e))
        int i0 = b * LS + t, i1 = i0 + 1024;
        float p0 = e0 * invZ, p1 = e1 * invZ;
        out_align[i0] = p0;
        out_align[i1] = p1;
        out_newcov[i0] = coverage[i0] + p0;
        out_newcov[i1] = coverage[i1] + p1;
    } else {
        int blk = blockIdx.x - 16;        // 0..63
        int tt = threadIdx.x & 255;
        int g = threadIdx.x >> 8;         // 0..3: each group sums 16 chunks
        int elem = blk * 256 + tt;        // 0..16383 = (b,h)
        int b = elem >> 10, h = elem & 1023;
        const float* p = cpart + (((size_t)(b * LCHUNK + g * 16)) << 10) + h;
        float s = 0.f;
        #pragma unroll
        for (int ch = 0; ch < 16; ++ch) s += p[(size_t)ch << 10];
        red4[g][tt] = s;
        __syncthreads();
        if (g == 0) csum[elem] = red4[0][tt] + red4[1][tt] + red4[2][tt] + red4[3][tt];
    }
}

// ---- 4: attn_h[b][h] = bout[h] + scale[b]*<Wout_c, csum[b]> + <Wout_q, query[b]> ----
__global__ void out_kernel(const float* __restrict__ csum, const float* __restrict__ query,
                           const float* __restrict__ Wout, const float* __restrict__ bout,
                           const float* __restrict__ scale, float* __restrict__ attn) {
    int h = blockIdx.x;
    int tid = threadIdx.x;            // 256
    int wv = tid >> 6, lane = tid & 63;
    int j0 = tid * 8;
    const float* wr = Wout + (size_t)h * (2 * HD);
    f4 w0 = ld4(wr + j0);
    f4 w1 = ld4(wr + j0 + 4);
    const float* src = (j0 < HD) ? (csum + j0) : (query + j0 - HD);   // waves 0,1: csum; 2,3: query
    __shared__ float red[4][NB];
    float acc[NB];
    #pragma unroll
    for (int b = 0; b < NB; ++b) {
        f4 x0 = ld4(src + b * HD);
        f4 x1 = ld4(src + b * HD + 4);
        acc[b] = w0.x * x0.x + w0.y * x0.y + w0.z * x0.z + w0.w * x0.w
               + w1.x * x1.x + w1.y * x1.y + w1.z * x1.z + w1.w * x1.w;
    }
    #pragma unroll
    for (int b = 0; b < NB; ++b) {
        float r = waveReduce(acc[b]);
        if (lane == 0) red[wv][b] = r;
    }
    __syncthreads();
    if (tid < NB) {
        float cpartial = red[0][tid] + red[1][tid];   // csum part
        float qpartial = red[2][tid] + red[3][tid];   // query part
        attn[tid * HD + h] = cpartial * scale[tid] + qpartial + bout[h];
    }
}

extern "C" void kernel_launch(void* const* d_in, const int* in_sizes, int n_in,
                              void* d_out, int out_size, void* d_ws, size_t ws_size,
                              hipStream_t stream) {
    const float* query    = (const float*)d_in[0];
    const float* states   = (const float*)d_in[1];
    const float* sf       = (const float*)d_in[2];
    const float* coverage = (const float*)d_in[3];
    const int*   mask     = (const int*)d_in[4];
    const int*   is_cov   = (const int*)d_in[5];
    const float* Wq       = (const float*)d_in[6];
    const float* bq       = (const float*)d_in[7];
    const float* Wc       = (const float*)d_in[8];
    const float* v        = (const float*)d_in[9];
    const float* Wout     = (const float*)d_in[10];
    const float* bout     = (const float*)d_in[11];

    float* out      = (float*)d_out;
    float* attn     = out;                 // (16,1,1024)  = 16384
    float* newcov   = out + 16384;         // (16,2048,1)  = 32768
    float* alignout = out + 49152;         // (16,2048,1)  = 32768

    float* w  = (float*)d_ws;
    float* qf      = w;                          // 16*1024    = 16384
    float* e       = w + 16384;                  // 16*2048    = 32768
    float* cpart   = w + 49152;                  // 16*64*1024 = 1048576
    float* scale   = w + 49152 + 1048576;        // 16
    float* csum    = scale + 16;                 // 16*1024

    // 1: query features (reads Wq once, 4 MB)
    qf_kernel<<<dim3(HD), dim3(256), 0, stream>>>(query, Wq, bq, qf);
    // 2: fused energies + raw-exp weighted partial contexts (~128 MB masked streams)
    fusedEC_kernel<<<dim3(LCHUNK, NB), dim3(256), 0, stream>>>(
        sf, qf, Wc, v, coverage, mask, is_cov, states, e, cpart);
    // 3: softmax finalize (align/newcov/scale) + cpart reduce, role-split
    mid_kernel<<<dim3(80), dim3(1024), 0, stream>>>(e, coverage, cpart, scale, csum, alignout, newcov);
    // 4: output projection (reads Wout once, 8 MB)
    out_kernel<<<dim3(HD), dim3(256), 0, stream>>>(csum, query, Wout, bout, scale, attn);
}